// Round 1
// baseline (3617.798 us; speedup 1.0000x reference)
//
#include <hip/hip_runtime.h>
#include <stdint.h>

#define NN 20000
#define MM 16000
#define DD 128

typedef unsigned long long u64;

// Monotone map fp32 -> u32 (order-preserving incl. negatives), pack with col so
// u64 compare == (dist, col) lexicographic min -> matches np.argmin tie-break.
__device__ __forceinline__ u64 pack_key(float v, int col) {
    unsigned u = __float_as_uint(v);
    u = (u & 0x80000000u) ? ~u : (u | 0x80000000u);
    return ((u64)u << 32) | (unsigned)col;
}

__global__ void k_init_keys(u64* keys) {
    int i = blockIdx.x * 256 + threadIdx.x;
    if (i < NN) keys[i] = ~0ull;
}

// One wave per rain row: y2[m] = ||rain[m]||^2
__global__ void k_y2(const float* __restrict__ rain, float* __restrict__ y2) {
    int row = blockIdx.x * 4 + (threadIdx.x >> 6);
    int lane = threadIdx.x & 63;
    if (row >= MM) return;
    float2 v = ((const float2*)(rain + (size_t)row * DD))[lane];
    float s = v.x * v.x + v.y * v.y;
    #pragma unroll
    for (int off = 32; off > 0; off >>= 1) s += __shfl_down(s, off);
    if (lane == 0) y2[row] = s;
}

// Fused distance GEMM + running argmin. Grid: (ceil(N/64), 5 M-splits).
// argmin_j of (y2[j] - 2*dot) == argmin of full squared distance.
#define TILES_PER_SPLIT 50   // 250 M-tiles of 64 / 5 splits

__global__ __launch_bounds__(256) void k_dist(const float* __restrict__ clear_f,
                                              const float* __restrict__ rain_f,
                                              const float* __restrict__ y2,
                                              u64* __restrict__ keys) {
    __shared__ float a_s[64][132];   // [row][k]  (+4 pad: 2-way-free b128 reads)
    __shared__ float b_s[64][68];    // [k][col] transposed, half-K at a time

    const int tid = threadIdx.x;
    const int tx = tid & 15;         // col group (4 cols)
    const int ty = tid >> 4;         // row group (4 rows)
    const int n0 = blockIdx.x * 64;

    // Stage A tile (64 rows x 128 k), coalesced float4, zero-pad rows >= N
    #pragma unroll
    for (int i = 0; i < 8; ++i) {
        int lin = i * 256 + tid;     // float4 index, 2048 total
        int row = lin >> 5;          // 32 float4 per row
        int kq = lin & 31;
        float4 v = make_float4(0.f, 0.f, 0.f, 0.f);
        int gr = n0 + row;
        if (gr < NN) v = ((const float4*)(clear_f + (size_t)gr * DD))[kq];
        *(float4*)&a_s[row][kq * 4] = v;
    }

    u64 best[4] = {~0ull, ~0ull, ~0ull, ~0ull};

    const int t0 = blockIdx.y * TILES_PER_SPLIT;
    for (int t = t0; t < t0 + TILES_PER_SPLIT; ++t) {
        const int m0 = t * 64;
        float acc[4][4] = {};
        #pragma unroll
        for (int half = 0; half < 2; ++half) {
            __syncthreads();
            // Stage B half-tile transposed: lanes span col at fixed kk ->
            // conflict-free LDS store; global is strided but L1-line-reused.
            #pragma unroll
            for (int i = 0; i < 16; ++i) {
                int lin = i * 256 + tid;   // 4096 scalars
                int col = lin & 63;
                int kk = lin >> 6;
                b_s[kk][col] = rain_f[(size_t)(m0 + col) * DD + half * 64 + kk];
            }
            __syncthreads();
            #pragma unroll
            for (int k = 0; k < 64; k += 4) {
                float4 b0 = *(const float4*)&b_s[k + 0][4 * tx];
                float4 b1v = *(const float4*)&b_s[k + 1][4 * tx];
                float4 b2v = *(const float4*)&b_s[k + 2][4 * tx];
                float4 b3v = *(const float4*)&b_s[k + 3][4 * tx];
                #pragma unroll
                for (int i = 0; i < 4; ++i) {
                    float4 a = *(const float4*)&a_s[4 * ty + i][half * 64 + k];
                    acc[i][0] += a.x * b0.x + a.y * b1v.x + a.z * b2v.x + a.w * b3v.x;
                    acc[i][1] += a.x * b0.y + a.y * b1v.y + a.z * b2v.y + a.w * b3v.y;
                    acc[i][2] += a.x * b0.z + a.y * b1v.z + a.z * b2v.z + a.w * b3v.z;
                    acc[i][3] += a.x * b0.w + a.y * b1v.w + a.z * b2v.w + a.w * b3v.w;
                }
            }
        }
        // Fold this tile into the running (dist, idx) min
        #pragma unroll
        for (int j = 0; j < 4; ++j) {
            int col = m0 + 4 * tx + j;
            float yv = y2[col];
            #pragma unroll
            for (int i = 0; i < 4; ++i) {
                float val = fmaf(-2.f, acc[i][j], yv);
                u64 key = pack_key(val, col);
                if (key < best[i]) best[i] = key;
            }
        }
    }

    // Reduce across the 16 tx lanes (same rows), then one atomicMin per row
    #pragma unroll
    for (int i = 0; i < 4; ++i) {
        u64 b = best[i];
        #pragma unroll
        for (int off = 1; off < 16; off <<= 1) {
            u64 o = __shfl_xor(b, off);
            if (o < b) b = o;
        }
        if (tx == 0) {
            int row = n0 + 4 * ty + i;
            if (row < NN) atomicMin(&keys[row], b);
        }
    }
}

// 16 rows per block: gather aligned, h=relu(comb@W1^T+b1), w=sigmoid(h@W2^T+b2),
// out = w*clear + (1-w)*aligned
__global__ __launch_bounds__(256) void k_mlp(const float* __restrict__ clear_f,
                                             const float* __restrict__ rain_f,
                                             const float* __restrict__ W1,
                                             const float* __restrict__ b1,
                                             const float* __restrict__ W2,
                                             const float* __restrict__ b2,
                                             const u64* __restrict__ keys,
                                             float* __restrict__ out) {
    __shared__ float comb_s[16][260];   // [row][0:128 clear | 128:256 aligned]
    __shared__ float w1_s[64][132];     // [kk][d] transposed tile
    __shared__ float red_s[16][17];
    __shared__ float w_s[16];

    const int tid = threadIdx.x;
    const int n0 = blockIdx.x * 16;

    // Phase 1: gather comb rows
    {
        int r = tid >> 4;
        int t = tid & 15;
        int n = n0 + r;
        unsigned idx = (unsigned)(keys[n] & 0xffffffffu);
        const float4* cp = (const float4*)(clear_f + (size_t)n * DD);
        const float4* rp = (const float4*)(rain_f + (size_t)idx * DD);
        *(float4*)&comb_s[r][4 * t] = cp[t];
        *(float4*)&comb_s[r][4 * (t + 16)] = cp[t + 16];
        *(float4*)&comb_s[r][DD + 4 * t] = rp[t];
        *(float4*)&comb_s[r][DD + 4 * (t + 16)] = rp[t + 16];
    }

    const int r = tid & 15;     // row this thread computes
    const int g = tid >> 4;     // output-d group
    const int d8 = g * 8;
    float h[8] = {};
    for (int kt = 0; kt < 4; ++kt) {
        __syncthreads();
        // Stage W1 k-tile transposed: lanes span d at fixed kk (conflict-free)
        #pragma unroll
        for (int i = 0; i < 32; ++i) {
            int lin = i * 256 + tid;   // 8192 scalars
            int d = lin & 127;
            int kk = lin >> 7;
            w1_s[kk][d] = W1[(size_t)d * 256 + kt * 64 + kk];
        }
        __syncthreads();
        #pragma unroll
        for (int kk = 0; kk < 64; ++kk) {
            float c = comb_s[r][kt * 64 + kk];
            float4 wa = *(const float4*)&w1_s[kk][d8];
            float4 wb = *(const float4*)&w1_s[kk][d8 + 4];
            h[0] = fmaf(c, wa.x, h[0]);
            h[1] = fmaf(c, wa.y, h[1]);
            h[2] = fmaf(c, wa.z, h[2]);
            h[3] = fmaf(c, wa.w, h[3]);
            h[4] = fmaf(c, wb.x, h[4]);
            h[5] = fmaf(c, wb.y, h[5]);
            h[6] = fmaf(c, wb.z, h[6]);
            h[7] = fmaf(c, wb.w, h[7]);
        }
    }
    // bias + relu, partial W2 dot
    float part = 0.f;
    #pragma unroll
    for (int j = 0; j < 8; ++j) {
        float hv = h[j] + b1[d8 + j];
        hv = hv > 0.f ? hv : 0.f;
        part = fmaf(hv, W2[d8 + j], part);
    }
    red_s[r][g] = part;
    __syncthreads();
    if (tid < 16) {
        float s = 0.f;
        #pragma unroll
        for (int g2 = 0; g2 < 16; ++g2) s += red_s[tid][g2];
        s += b2[0];
        w_s[tid] = 1.f / (1.f + expf(-s));
    }
    __syncthreads();
    // Gated output, coalesced
    {
        int rw = tid >> 4;
        int c8 = (tid & 15) * 8;
        float wv = w_s[rw];
        float4 o0, o1;
        float* op = (float*)&o0;
        #pragma unroll
        for (int j = 0; j < 8; ++j) {
            float cv = comb_s[rw][c8 + j];
            float av = comb_s[rw][DD + c8 + j];
            ((float*)&o0)[j < 4 ? j : 0] = 0.f; // placeholder overwritten below
        }
        (void)op;
        float ov[8];
        #pragma unroll
        for (int j = 0; j < 8; ++j) {
            float cv = comb_s[rw][c8 + j];
            float av = comb_s[rw][DD + c8 + j];
            ov[j] = wv * cv + (1.f - wv) * av;
        }
        float4* o = (float4*)(out + (size_t)(n0 + rw) * DD + c8);
        o[0] = make_float4(ov[0], ov[1], ov[2], ov[3]);
        o[1] = make_float4(ov[4], ov[5], ov[6], ov[7]);
    }
}

extern "C" void kernel_launch(void* const* d_in, const int* in_sizes, int n_in,
                              void* d_out, int out_size, void* d_ws, size_t ws_size,
                              hipStream_t stream) {
    const float* clear_f = (const float*)d_in[0];
    const float* rain_f = (const float*)d_in[1];
    const float* W1 = (const float*)d_in[2];
    const float* b1 = (const float*)d_in[3];
    const float* W2 = (const float*)d_in[4];
    const float* b2 = (const float*)d_in[5];
    float* out = (float*)d_out;

    u64* keys = (u64*)d_ws;                                   // N u64
    float* y2 = (float*)((char*)d_ws + (size_t)NN * sizeof(u64)); // M f32

    k_init_keys<<<(NN + 255) / 256, 256, 0, stream>>>(keys);
    k_y2<<<MM / 4, 256, 0, stream>>>(rain_f, y2);
    k_dist<<<dim3((NN + 63) / 64, 5), 256, 0, stream>>>(clear_f, rain_f, y2, keys);
    k_mlp<<<NN / 16, 256, 0, stream>>>(clear_f, rain_f, W1, b1, W2, b2, keys, out);
}

// Round 2
// 418.078 us; speedup vs baseline: 8.6534x; 8.6534x over previous
//
#include <hip/hip_runtime.h>
#include <stdint.h>

#define NN 20000
#define MM 16000
#define DD 128
#define NTILES_M 125   // 16000 / 128
#define SPLITS 8
#define NBLK 157       // ceil(20000/128)

typedef unsigned long long u64;
typedef _Float16 f16x8 __attribute__((ext_vector_type(8)));
typedef float f32x16 __attribute__((ext_vector_type(16)));

__global__ void k_init_keys(u64* keys) {
    int i = blockIdx.x * 256 + threadIdx.x;
    if (i < NN) keys[i] = ~0ull;
}

// One wave per rain row: y2[m] = ||rain[m]||^2 (fp32)
__global__ void k_y2(const float* __restrict__ rain, float* __restrict__ y2) {
    int row = blockIdx.x * 4 + (threadIdx.x >> 6);
    int lane = threadIdx.x & 63;
    if (row >= MM) return;
    float2 v = ((const float2*)(rain + (size_t)row * DD))[lane];
    float s = v.x * v.x + v.y * v.y;
    #pragma unroll
    for (int off = 32; off > 0; off >>= 1) s += __shfl_down(s, off);
    if (lane == 0) y2[row] = s;
}

// Split (-2*clear) into fp16 hi/lo, row-major [NN][128]
__global__ void k_split_A(const float* __restrict__ clear_f,
                          _Float16* __restrict__ Ahi, _Float16* __restrict__ Alo) {
    int id = blockIdx.x * 256 + threadIdx.x;
    if (id >= NN * 16) return;
    int row = id >> 4, kc = id & 15;
    const float4* src = (const float4*)(clear_f + (size_t)row * DD + kc * 8);
    float4 v0 = src[0], v1 = src[1];
    float x[8] = {v0.x, v0.y, v0.z, v0.w, v1.x, v1.y, v1.z, v1.w};
    _Float16 hi[8], lo[8];
    #pragma unroll
    for (int j = 0; j < 8; ++j) {
        float s = -2.f * x[j];
        _Float16 h = (_Float16)s;
        hi[j] = h;
        lo[j] = (_Float16)(s - (float)h);
    }
    *(f16x8*)(Ahi + (size_t)row * DD + (size_t)kc * 8) = *(f16x8*)hi;
    *(f16x8*)(Alo + (size_t)row * DD + (size_t)kc * 8) = *(f16x8*)lo;
}

// Split rain into fp16 hi/lo, written as per-M-tile LDS images:
// tile image = 32768 f16 (64KB): hi chunks [0..2047], lo chunks [2048..4095],
// chunk(col c, kpair kp) = ((kstep*4 + cg)*2 + kh)*32 + cc
//   (cg=c>>5, cc=c&31, kstep=kp>>1, kh=kp&1), chunk payload = 8 consecutive k.
__global__ void k_split_B(const float* __restrict__ rain, _Float16* __restrict__ Bimg) {
    int id = blockIdx.x * 256 + threadIdx.x;
    if (id >= MM * 16) return;
    int row = id >> 4, kp = id & 15;
    int tile = row >> 7, c = row & 127;
    int cg = c >> 5, cc = c & 31;
    int kstep = kp >> 1, kh = kp & 1;
    int chunk = ((kstep * 4 + cg) * 2 + kh) * 32 + cc;
    const float4* src = (const float4*)(rain + (size_t)row * DD + kp * 8);
    float4 v0 = src[0], v1 = src[1];
    float x[8] = {v0.x, v0.y, v0.z, v0.w, v1.x, v1.y, v1.z, v1.w};
    _Float16 hi[8], lo[8];
    #pragma unroll
    for (int j = 0; j < 8; ++j) {
        _Float16 h = (_Float16)x[j];
        hi[j] = h;
        lo[j] = (_Float16)(x[j] - (float)h);
    }
    size_t tbase = (size_t)tile * 32768;
    *(f16x8*)(Bimg + tbase + (size_t)chunk * 8) = *(f16x8*)hi;
    *(f16x8*)(Bimg + tbase + 16384 + (size_t)chunk * 8) = *(f16x8*)lo;
}

// MFMA distance GEMM + fused argmin.
// acc = sum_k (-2*clear)*rain via fp16 split (hh + hl + lh); d = acc + y2[col].
// Block: 128 rows x 128 cols; wave w handles rows 32w..32w+31 over all 128 cols.
__global__ __launch_bounds__(256, 2) void k_dist(
        const _Float16* __restrict__ Ahi, const _Float16* __restrict__ Alo,
        const _Float16* __restrict__ Bimg, const float* __restrict__ y2,
        u64* __restrict__ keys) {
    __shared__ _Float16 lds[32768];   // 64KB: exact B tile image

    const int tid = threadIdx.x;
    const int w = tid >> 6, lane = tid & 63;
    const int l5 = lane >> 5, l31 = lane & 31;
    const int id = blockIdx.x;
    const int split = id & 7;             // == XCD round-robin -> L2 locality
    const int n0 = (id >> 3) * 128;

    // A fragments in registers, full K: lane holds A[row=l31][k=ks*16+l5*8+j]
    int arow = n0 + w * 32 + l31;
    if (arow >= NN) arow = NN - 1;
    const _Float16* ap = Ahi + (size_t)arow * DD + l5 * 8;
    const _Float16* lp = Alo + (size_t)arow * DD + l5 * 8;
    f16x8 afh[8], afl[8];
    #pragma unroll
    for (int ks = 0; ks < 8; ++ks) {
        afh[ks] = *(const f16x8*)(ap + ks * 16);
        afl[ks] = *(const f16x8*)(lp + ks * 16);
    }

    float bestd[16];
    int bestcol[16];
    #pragma unroll
    for (int r = 0; r < 16; ++r) { bestd[r] = 1e30f; bestcol[r] = 0; }

    for (int t = split; t < NTILES_M; t += SPLITS) {
        float y2v[4];
        #pragma unroll
        for (int cg = 0; cg < 4; ++cg) y2v[cg] = y2[t * 128 + cg * 32 + l31];

        // stage 64KB tile image: 64 wave-segments of 1KB, width-16 direct-to-LDS
        {
            const _Float16* gsrc = Bimg + (size_t)t * 32768;
            #pragma unroll
            for (int n = 0; n < 16; ++n) {
                int seg = w * 16 + n;                       // 0..63
                const _Float16* gp = gsrc + (size_t)seg * 512 + (size_t)lane * 8;
                _Float16* dst = lds + (size_t)seg * 512;
                __builtin_amdgcn_global_load_lds(
                    (const __attribute__((address_space(1))) unsigned int*)gp,
                    (__attribute__((address_space(3))) unsigned int*)dst,
                    16, 0, 0);
            }
        }
        __syncthreads();

        f32x16 acc[4];
        #pragma unroll
        for (int cg = 0; cg < 4; ++cg)
            #pragma unroll
            for (int e = 0; e < 16; ++e) acc[cg][e] = 0.f;

        #pragma unroll
        for (int ks = 0; ks < 8; ++ks) {
            f16x8 bh[4], bl[4];
            #pragma unroll
            for (int cg = 0; cg < 4; ++cg) {
                int chunk = (ks * 4 + cg) * 64 + lane;      // lane-linear b128
                bh[cg] = *(const f16x8*)(lds + (size_t)chunk * 8);
                bl[cg] = *(const f16x8*)(lds + 16384 + (size_t)chunk * 8);
            }
            #pragma unroll
            for (int cg = 0; cg < 4; ++cg) {
                acc[cg] = __builtin_amdgcn_mfma_f32_32x32x16_f16(afh[ks], bh[cg], acc[cg], 0, 0, 0);
                acc[cg] = __builtin_amdgcn_mfma_f32_32x32x16_f16(afh[ks], bl[cg], acc[cg], 0, 0, 0);
                acc[cg] = __builtin_amdgcn_mfma_f32_32x32x16_f16(afl[ks], bh[cg], acc[cg], 0, 0, 0);
            }
        }

        // fold tile into running per-row argmin (exact col tracking)
        int cb0 = t * 128 + l31;
        #pragma unroll
        for (int r = 0; r < 16; ++r) {
            float d0 = acc[0][r] + y2v[0];
            float d1 = acc[1][r] + y2v[1];
            float d2 = acc[2][r] + y2v[2];
            float d3 = acc[3][r] + y2v[3];
            float tmin = fminf(fminf(d0, d1), fminf(d2, d3));
            int nc = (d0 <= tmin) ? cb0
                   : (d1 <= tmin) ? cb0 + 32
                   : (d2 <= tmin) ? cb0 + 64 : cb0 + 96;
            bool upd = tmin < bestd[r];
            bestd[r] = upd ? tmin : bestd[r];
            bestcol[r] = upd ? nc : bestcol[r];
        }
        __syncthreads();
    }

    // cross-lane min within each 32-lane half (rows differ by l5), then atomics.
    // C/D layout (verified m74/m101): col=lane&31, row=(reg&3)+8*(reg>>2)+4*(lane>>5)
    #pragma unroll
    for (int r = 0; r < 16; ++r) {
        unsigned u = __float_as_uint(bestd[r]);
        u ^= (unsigned)((int)u >> 31) | 0x80000000u;        // monotone flip
        u64 key = ((u64)u << 32) | (unsigned)bestcol[r];
        #pragma unroll
        for (int off = 1; off < 32; off <<= 1) {
            u64 o = __shfl_xor(key, off);
            if (o < key) key = o;
        }
        if (l31 == 0) {
            int grow = n0 + w * 32 + (r & 3) + 8 * (r >> 2) + 4 * l5;
            if (grow < NN) atomicMin(&keys[grow], key);
        }
    }
}

// 16 rows per block: gather aligned, h=relu(comb@W1^T+b1), w=sigmoid(h@W2^T+b2),
// out = w*clear + (1-w)*aligned
__global__ __launch_bounds__(256) void k_mlp(const float* __restrict__ clear_f,
                                             const float* __restrict__ rain_f,
                                             const float* __restrict__ W1,
                                             const float* __restrict__ b1,
                                             const float* __restrict__ W2,
                                             const float* __restrict__ b2,
                                             const u64* __restrict__ keys,
                                             float* __restrict__ out) {
    __shared__ float comb_s[16][260];
    __shared__ float w1_s[64][132];
    __shared__ float red_s[16][17];
    __shared__ float w_s[16];

    const int tid = threadIdx.x;
    const int n0 = blockIdx.x * 16;

    {
        int r = tid >> 4;
        int t = tid & 15;
        int n = n0 + r;
        unsigned idx = (unsigned)(keys[n] & 0xffffffffu);
        const float4* cp = (const float4*)(clear_f + (size_t)n * DD);
        const float4* rp = (const float4*)(rain_f + (size_t)idx * DD);
        *(float4*)&comb_s[r][4 * t] = cp[t];
        *(float4*)&comb_s[r][4 * (t + 16)] = cp[t + 16];
        *(float4*)&comb_s[r][DD + 4 * t] = rp[t];
        *(float4*)&comb_s[r][DD + 4 * (t + 16)] = rp[t + 16];
    }

    const int r = tid & 15;
    const int g = tid >> 4;
    const int d8 = g * 8;
    float h[8] = {};
    for (int kt = 0; kt < 4; ++kt) {
        __syncthreads();
        #pragma unroll
        for (int i = 0; i < 32; ++i) {
            int lin = i * 256 + tid;
            int d = lin & 127;
            int kk = lin >> 7;
            w1_s[kk][d] = W1[(size_t)d * 256 + kt * 64 + kk];
        }
        __syncthreads();
        #pragma unroll
        for (int kk = 0; kk < 64; ++kk) {
            float c = comb_s[r][kt * 64 + kk];
            float4 wa = *(const float4*)&w1_s[kk][d8];
            float4 wb = *(const float4*)&w1_s[kk][d8 + 4];
            h[0] = fmaf(c, wa.x, h[0]);
            h[1] = fmaf(c, wa.y, h[1]);
            h[2] = fmaf(c, wa.z, h[2]);
            h[3] = fmaf(c, wa.w, h[3]);
            h[4] = fmaf(c, wb.x, h[4]);
            h[5] = fmaf(c, wb.y, h[5]);
            h[6] = fmaf(c, wb.z, h[6]);
            h[7] = fmaf(c, wb.w, h[7]);
        }
    }
    float part = 0.f;
    #pragma unroll
    for (int j = 0; j < 8; ++j) {
        float hv = h[j] + b1[d8 + j];
        hv = hv > 0.f ? hv : 0.f;
        part = fmaf(hv, W2[d8 + j], part);
    }
    red_s[r][g] = part;
    __syncthreads();
    if (tid < 16) {
        float s = 0.f;
        #pragma unroll
        for (int g2 = 0; g2 < 16; ++g2) s += red_s[tid][g2];
        s += b2[0];
        w_s[tid] = 1.f / (1.f + expf(-s));
    }
    __syncthreads();
    {
        int rw = tid >> 4;
        int c8 = (tid & 15) * 8;
        float wv = w_s[rw];
        float ov[8];
        #pragma unroll
        for (int j = 0; j < 8; ++j) {
            float cv = comb_s[rw][c8 + j];
            float av = comb_s[rw][DD + c8 + j];
            ov[j] = wv * cv + (1.f - wv) * av;
        }
        float4* o = (float4*)(out + (size_t)(n0 + rw) * DD + c8);
        o[0] = make_float4(ov[0], ov[1], ov[2], ov[3]);
        o[1] = make_float4(ov[4], ov[5], ov[6], ov[7]);
    }
}

extern "C" void kernel_launch(void* const* d_in, const int* in_sizes, int n_in,
                              void* d_out, int out_size, void* d_ws, size_t ws_size,
                              hipStream_t stream) {
    const float* clear_f = (const float*)d_in[0];
    const float* rain_f = (const float*)d_in[1];
    const float* W1 = (const float*)d_in[2];
    const float* b1 = (const float*)d_in[3];
    const float* W2 = (const float*)d_in[4];
    const float* b2 = (const float*)d_in[5];
    float* out = (float*)d_out;

    char* ws = (char*)d_ws;
    u64* keys = (u64*)ws;                                  // 160,000 B
    float* y2 = (float*)(ws + 160000);                     // 64,000 B
    _Float16* Ahi = (_Float16*)(ws + 224000);              // 5,120,000 B
    _Float16* Alo = (_Float16*)(ws + 5344000);             // 5,120,000 B
    _Float16* Bimg = (_Float16*)(ws + 10464000);           // 8,192,000 B

    k_init_keys<<<(NN + 255) / 256, 256, 0, stream>>>(keys);
    k_y2<<<MM / 4, 256, 0, stream>>>(rain_f, y2);
    k_split_A<<<(NN * 16 + 255) / 256, 256, 0, stream>>>(clear_f, Ahi, Alo);
    k_split_B<<<(MM * 16 + 255) / 256, 256, 0, stream>>>(rain_f, Bimg);
    k_dist<<<NBLK * SPLITS, 256, 0, stream>>>(Ahi, Alo, Bimg, y2, keys);
    k_mlp<<<NN / 16, 256, 0, stream>>>(clear_f, rain_f, W1, b1, W2, b2, keys, out);
}

// Round 3
// 393.494 us; speedup vs baseline: 9.1940x; 1.0625x over previous
//
#include <hip/hip_runtime.h>
#include <stdint.h>

#define NN 20000
#define MM 16000
#define DD 128
#define CT 500        // 16000 / 32 col-tiles
#define SPLITS 13
#define RB 79         // ceil(20000/256) row blocks

typedef unsigned long long u64;
typedef _Float16 f16x8 __attribute__((ext_vector_type(8)));
typedef float f32x16 __attribute__((ext_vector_type(16)));

__global__ void k_init_keys(u64* keys) {
    int i = blockIdx.x * 256 + threadIdx.x;
    if (i < NN) keys[i] = ~0ull;
}

// One wave per rain row: y2[m] = ||rain[m]||^2 (fp32)
__global__ void k_y2(const float* __restrict__ rain, float* __restrict__ y2) {
    int row = blockIdx.x * 4 + (threadIdx.x >> 6);
    int lane = threadIdx.x & 63;
    if (row >= MM) return;
    float2 v = ((const float2*)(rain + (size_t)row * DD))[lane];
    float s = v.x * v.x + v.y * v.y;
    #pragma unroll
    for (int off = 32; off > 0; off >>= 1) s += __shfl_down(s, off);
    if (lane == 0) y2[row] = s;
}

// Split (-2*clear) into fp16 hi/lo, row-major [NN][128]
__global__ void k_split_A(const float* __restrict__ clear_f,
                          _Float16* __restrict__ Ahi, _Float16* __restrict__ Alo) {
    int id = blockIdx.x * 256 + threadIdx.x;
    if (id >= NN * 16) return;
    int row = id >> 4, kc = id & 15;
    const float4* src = (const float4*)(clear_f + (size_t)row * DD + kc * 8);
    float4 v0 = src[0], v1 = src[1];
    float x[8] = {v0.x, v0.y, v0.z, v0.w, v1.x, v1.y, v1.z, v1.w};
    _Float16 hi[8], lo[8];
    #pragma unroll
    for (int j = 0; j < 8; ++j) {
        float s = -2.f * x[j];
        _Float16 h = (_Float16)s;
        hi[j] = h;
        lo[j] = (_Float16)(s - (float)h);
    }
    *(f16x8*)(Ahi + (size_t)row * DD + (size_t)kc * 8) = *(f16x8*)hi;
    *(f16x8*)(Alo + (size_t)row * DD + (size_t)kc * 8) = *(f16x8*)lo;
}

// Split rain into fp16 hi/lo 32-col tile images (16KB per tile):
// tile tc: hi f16[0:4096], lo f16[4096:8192]
// chunk(ks,kh,cl) = (ks*2+kh)*32 + cl, payload = 8 consecutive k (k=ks*16+kh*8+j)
// Thread mapping: cl fast across lanes -> coalesced 512B store runs.
__global__ void k_split_B(const float* __restrict__ rain, _Float16* __restrict__ Bimg) {
    int id = blockIdx.x * 256 + threadIdx.x;
    if (id >= MM * 16) return;
    int cl = id & 31;
    int kp = (id >> 5) & 15;
    int tc = id >> 9;                       // 500 tiles
    int row = tc * 32 + cl;
    const float4* src = (const float4*)(rain + (size_t)row * DD + kp * 8);
    float4 v0 = src[0], v1 = src[1];
    float x[8] = {v0.x, v0.y, v0.z, v0.w, v1.x, v1.y, v1.z, v1.w};
    _Float16 hi[8], lo[8];
    #pragma unroll
    for (int j = 0; j < 8; ++j) {
        _Float16 h = (_Float16)x[j];
        hi[j] = h;
        lo[j] = (_Float16)(x[j] - (float)h);
    }
    size_t base = (size_t)tc * 8192;
    int chunk = kp * 32 + cl;               // (ks*2+kh)*32+cl
    *(f16x8*)(Bimg + base + (size_t)chunk * 8) = *(f16x8*)hi;
    *(f16x8*)(Bimg + base + 4096 + (size_t)chunk * 8) = *(f16x8*)lo;
}

// MFMA distance GEMM + fused argmin, double-buffered B tiles.
// Block: 256 rows x 32-col tiles; wave w: rows 64w..64w+63 (2 row-blocks).
__global__ __launch_bounds__(256, 2) void k_dist(
        const _Float16* __restrict__ Ahi, const _Float16* __restrict__ Alo,
        const _Float16* __restrict__ Bimg, const float* __restrict__ y2,
        u64* __restrict__ keys) {
    __shared__ _Float16 lds[2][8192];   // 2 x 16KB B-tile images

    const int tid = threadIdx.x;
    const int w = tid >> 6, lane = tid & 63;
    const int l5 = lane >> 5, l31 = lane & 31;
    const int split = blockIdx.y;
    const int n0 = blockIdx.x * 256;

    // A fragments in registers, full K, 2 row-blocks:
    // lane holds A[row = l31][k = ks*16 + l5*8 + j]
    f16x8 afh0[8], afl0[8], afh1[8], afl1[8];
    {
        int r0 = n0 + w * 64 + l31;       if (r0 >= NN) r0 = NN - 1;
        int r1 = n0 + w * 64 + 32 + l31;  if (r1 >= NN) r1 = NN - 1;
        const _Float16* h0 = Ahi + (size_t)r0 * DD + l5 * 8;
        const _Float16* o0 = Alo + (size_t)r0 * DD + l5 * 8;
        const _Float16* h1 = Ahi + (size_t)r1 * DD + l5 * 8;
        const _Float16* o1 = Alo + (size_t)r1 * DD + l5 * 8;
        #pragma unroll
        for (int ks = 0; ks < 8; ++ks) {
            afh0[ks] = *(const f16x8*)(h0 + ks * 16);
            afl0[ks] = *(const f16x8*)(o0 + ks * 16);
            afh1[ks] = *(const f16x8*)(h1 + ks * 16);
            afl1[ks] = *(const f16x8*)(o1 + ks * 16);
        }
    }

    float bestd[32];
    int bestcol[32];
    #pragma unroll
    for (int s = 0; s < 32; ++s) { bestd[s] = 1e30f; bestcol[s] = 0; }

    const int nt = (CT - split + SPLITS - 1) / SPLITS;   // tiles for this split

    // Prologue: stage tile 0 into buf 0 (16 segs of 1KB; 4 per wave)
    {
        const _Float16* gsrc = Bimg + (size_t)split * 8192;
        #pragma unroll
        for (int n = 0; n < 4; ++n) {
            int seg = w * 4 + n;
            __builtin_amdgcn_global_load_lds(
                (const __attribute__((address_space(1))) unsigned int*)
                    (gsrc + (size_t)seg * 512 + (size_t)lane * 8),
                (__attribute__((address_space(3))) unsigned int*)
                    (&lds[0][0] + (size_t)seg * 512),
                16, 0, 0);
        }
    }
    __syncthreads();

    int p = 0;
    for (int i = 0; i < nt; ++i) {
        const int t = split + i * SPLITS;

        // Prefetch next tile into the other buffer (overlaps this compute)
        if (i + 1 < nt) {
            const _Float16* gsrc = Bimg + (size_t)(t + SPLITS) * 8192;
            _Float16* lbase = &lds[1 - p][0];
            #pragma unroll
            for (int n = 0; n < 4; ++n) {
                int seg = w * 4 + n;
                __builtin_amdgcn_global_load_lds(
                    (const __attribute__((address_space(1))) unsigned int*)
                        (gsrc + (size_t)seg * 512 + (size_t)lane * 8),
                    (__attribute__((address_space(3))) unsigned int*)
                        (lbase + (size_t)seg * 512),
                    16, 0, 0);
            }
        }

        float y2v = y2[t * 32 + l31];

        f32x16 acc0, acc1;
        #pragma unroll
        for (int e = 0; e < 16; ++e) { acc0[e] = 0.f; acc1[e] = 0.f; }

        const _Float16* lbuf = &lds[p][0];
        #pragma unroll
        for (int ks = 0; ks < 8; ++ks) {
            f16x8 bh = *(const f16x8*)(lbuf + (size_t)ks * 512 + (size_t)lane * 8);
            f16x8 bl = *(const f16x8*)(lbuf + 4096 + (size_t)ks * 512 + (size_t)lane * 8);
            acc0 = __builtin_amdgcn_mfma_f32_32x32x16_f16(afh0[ks], bh, acc0, 0, 0, 0);
            acc1 = __builtin_amdgcn_mfma_f32_32x32x16_f16(afh1[ks], bh, acc1, 0, 0, 0);
            acc0 = __builtin_amdgcn_mfma_f32_32x32x16_f16(afh0[ks], bl, acc0, 0, 0, 0);
            acc1 = __builtin_amdgcn_mfma_f32_32x32x16_f16(afh1[ks], bl, acc1, 0, 0, 0);
            acc0 = __builtin_amdgcn_mfma_f32_32x32x16_f16(afl0[ks], bh, acc0, 0, 0, 0);
            acc1 = __builtin_amdgcn_mfma_f32_32x32x16_f16(afl1[ks], bh, acc1, 0, 0, 0);
        }

        // Fold tile into running per-row argmin (col = t*32 + l31)
        int col = t * 32 + l31;
        #pragma unroll
        for (int e = 0; e < 16; ++e) {
            float d0 = acc0[e] + y2v;
            bool u0 = d0 < bestd[e];
            bestd[e] = u0 ? d0 : bestd[e];
            bestcol[e] = u0 ? col : bestcol[e];
            float d1 = acc1[e] + y2v;
            bool u1 = d1 < bestd[16 + e];
            bestd[16 + e] = u1 ? d1 : bestd[16 + e];
            bestcol[16 + e] = u1 ? col : bestcol[16 + e];
        }

        __syncthreads();   // drains prefetch (long in flight) + frees buf p
        p ^= 1;
    }

    // Cross-lane min over l31 group, then one atomicMin per row.
    // C/D layout: col=lane&31, row=(e&3)+8*(e>>2)+4*l5
    #pragma unroll
    for (int s = 0; s < 32; ++s) {
        unsigned u = __float_as_uint(bestd[s]);
        u = (u & 0x80000000u) ? ~u : (u | 0x80000000u);
        u64 key = ((u64)u << 32) | (unsigned)bestcol[s];
        #pragma unroll
        for (int off = 1; off < 32; off <<= 1) {
            u64 o = __shfl_xor(key, off);
            if (o < key) key = o;
        }
        if (l31 == 0) {
            int e = s & 15, rb = s >> 4;
            int grow = n0 + w * 64 + rb * 32 + (e & 3) + 8 * (e >> 2) + 4 * l5;
            if (grow < NN) atomicMin(&keys[grow], key);
        }
    }
}

// 16 rows per block: gather aligned, h=relu(comb@W1^T+b1), w=sigmoid(h@W2^T+b2),
// out = w*clear + (1-w)*aligned
__global__ __launch_bounds__(256) void k_mlp(const float* __restrict__ clear_f,
                                             const float* __restrict__ rain_f,
                                             const float* __restrict__ W1,
                                             const float* __restrict__ b1,
                                             const float* __restrict__ W2,
                                             const float* __restrict__ b2,
                                             const u64* __restrict__ keys,
                                             float* __restrict__ out) {
    __shared__ float comb_s[16][260];
    __shared__ float w1_s[64][133];     // [kk][d], stride 133: 2-way-free banks
    __shared__ float red_s[16][17];
    __shared__ float w_s[16];

    const int tid = threadIdx.x;
    const int n0 = blockIdx.x * 16;

    {
        int r = tid >> 4;
        int t = tid & 15;
        int n = n0 + r;
        unsigned idx = (unsigned)(keys[n] & 0xffffffffu);
        const float4* cp = (const float4*)(clear_f + (size_t)n * DD);
        const float4* rp = (const float4*)(rain_f + (size_t)idx * DD);
        *(float4*)&comb_s[r][4 * t] = cp[t];
        *(float4*)&comb_s[r][4 * (t + 16)] = cp[t + 16];
        *(float4*)&comb_s[r][DD + 4 * t] = rp[t];
        *(float4*)&comb_s[r][DD + 4 * (t + 16)] = rp[t + 16];
    }

    const int r = tid & 15;
    const int g = tid >> 4;
    const int d8 = g * 8;
    float h[8] = {};
    for (int kt = 0; kt < 4; ++kt) {
        __syncthreads();
        // Stage W1 k-tile: lanes span kk (coalesced global); LDS stride-133.
        #pragma unroll
        for (int i = 0; i < 32; ++i) {
            int lin = i * 256 + tid;
            int kk = lin & 63;
            int d = lin >> 6;
            w1_s[kk][d] = W1[(size_t)d * 256 + kt * 64 + kk];
        }
        __syncthreads();
        #pragma unroll
        for (int kk = 0; kk < 64; ++kk) {
            float c = comb_s[r][kt * 64 + kk];
            float4 wa = *(const float4*)&w1_s[kk][d8];
            float4 wb = *(const float4*)&w1_s[kk][d8 + 4];
            h[0] = fmaf(c, wa.x, h[0]);
            h[1] = fmaf(c, wa.y, h[1]);
            h[2] = fmaf(c, wa.z, h[2]);
            h[3] = fmaf(c, wa.w, h[3]);
            h[4] = fmaf(c, wb.x, h[4]);
            h[5] = fmaf(c, wb.y, h[5]);
            h[6] = fmaf(c, wb.z, h[6]);
            h[7] = fmaf(c, wb.w, h[7]);
        }
    }
    float part = 0.f;
    #pragma unroll
    for (int j = 0; j < 8; ++j) {
        float hv = h[j] + b1[d8 + j];
        hv = hv > 0.f ? hv : 0.f;
        part = fmaf(hv, W2[d8 + j], part);
    }
    red_s[r][g] = part;
    __syncthreads();
    if (tid < 16) {
        float s = 0.f;
        #pragma unroll
        for (int g2 = 0; g2 < 16; ++g2) s += red_s[tid][g2];
        s += b2[0];
        w_s[tid] = 1.f / (1.f + expf(-s));
    }
    __syncthreads();
    {
        int rw = tid >> 4;
        int c8 = (tid & 15) * 8;
        float wv = w_s[rw];
        float ov[8];
        #pragma unroll
        for (int j = 0; j < 8; ++j) {
            float cv = comb_s[rw][c8 + j];
            float av = comb_s[rw][DD + c8 + j];
            ov[j] = wv * cv + (1.f - wv) * av;
        }
        float4* o = (float4*)(out + (size_t)(n0 + rw) * DD + c8);
        o[0] = make_float4(ov[0], ov[1], ov[2], ov[3]);
        o[1] = make_float4(ov[4], ov[5], ov[6], ov[7]);
    }
}

extern "C" void kernel_launch(void* const* d_in, const int* in_sizes, int n_in,
                              void* d_out, int out_size, void* d_ws, size_t ws_size,
                              hipStream_t stream) {
    const float* clear_f = (const float*)d_in[0];
    const float* rain_f = (const float*)d_in[1];
    const float* W1 = (const float*)d_in[2];
    const float* b1 = (const float*)d_in[3];
    const float* W2 = (const float*)d_in[4];
    const float* b2 = (const float*)d_in[5];
    float* out = (float*)d_out;

    char* ws = (char*)d_ws;
    u64* keys = (u64*)ws;                                  // 160,000 B
    float* y2 = (float*)(ws + 160000);                     // 64,000 B
    _Float16* Ahi = (_Float16*)(ws + 224000);              // 5,120,000 B
    _Float16* Alo = (_Float16*)(ws + 5344000);             // 5,120,000 B
    _Float16* Bimg = (_Float16*)(ws + 10464000);           // 8,192,000 B

    k_init_keys<<<(NN + 255) / 256, 256, 0, stream>>>(keys);
    k_y2<<<MM / 4, 256, 0, stream>>>(rain_f, y2);
    k_split_A<<<(NN * 16 + 255) / 256, 256, 0, stream>>>(clear_f, Ahi, Alo);
    k_split_B<<<(MM * 16 + 255) / 256, 256, 0, stream>>>(rain_f, Bimg);
    k_dist<<<dim3(RB, SPLITS), 256, 0, stream>>>(Ahi, Alo, Bimg, y2, keys);
    k_mlp<<<NN / 16, 256, 0, stream>>>(clear_f, rain_f, W1, b1, W2, b2, keys, out);
}

// Round 4
// 380.974 us; speedup vs baseline: 9.4962x; 1.0329x over previous
//
#include <hip/hip_runtime.h>
#include <stdint.h>

#define NN 20000
#define MM 16000
#define DD 128
#define CT 500        // 16000 / 32 col-tiles
#define SPLITS 24     // multiple of 8 -> split % 8 == XCD id (L2 locality)
#define RB 79         // ceil(20000/256) row blocks

typedef unsigned long long u64;
typedef _Float16 f16x8 __attribute__((ext_vector_type(8)));
typedef float f32x16 __attribute__((ext_vector_type(16)));

__global__ void k_init_keys(u64* keys) {
    int i = blockIdx.x * 256 + threadIdx.x;
    if (i < NN) keys[i] = ~0ull;
}

// One wave per rain row: y2[m] = ||rain[m]||^2 (fp32)
__global__ void k_y2(const float* __restrict__ rain, float* __restrict__ y2) {
    int row = blockIdx.x * 4 + (threadIdx.x >> 6);
    int lane = threadIdx.x & 63;
    if (row >= MM) return;
    float2 v = ((const float2*)(rain + (size_t)row * DD))[lane];
    float s = v.x * v.x + v.y * v.y;
    #pragma unroll
    for (int off = 32; off > 0; off >>= 1) s += __shfl_down(s, off);
    if (lane == 0) y2[row] = s;
}

// Split (-2*clear) into fp16 hi/lo, row-major [NN][128]
__global__ void k_split_A(const float* __restrict__ clear_f,
                          _Float16* __restrict__ Ahi, _Float16* __restrict__ Alo) {
    int id = blockIdx.x * 256 + threadIdx.x;
    if (id >= NN * 16) return;
    int row = id >> 4, kc = id & 15;
    const float4* src = (const float4*)(clear_f + (size_t)row * DD + kc * 8);
    float4 v0 = src[0], v1 = src[1];
    float x[8] = {v0.x, v0.y, v0.z, v0.w, v1.x, v1.y, v1.z, v1.w};
    _Float16 hi[8], lo[8];
    #pragma unroll
    for (int j = 0; j < 8; ++j) {
        float s = -2.f * x[j];
        _Float16 h = (_Float16)s;
        hi[j] = h;
        lo[j] = (_Float16)(s - (float)h);
    }
    *(f16x8*)(Ahi + (size_t)row * DD + (size_t)kc * 8) = *(f16x8*)hi;
    *(f16x8*)(Alo + (size_t)row * DD + (size_t)kc * 8) = *(f16x8*)lo;
}

// Split rain into fp16 hi/lo 32-col tile images (16KB per tile):
// tile tc: hi f16[0:4096], lo f16[4096:8192]
// chunk(ks,kh,cl) = (ks*2+kh)*32 + cl, payload = 8 consecutive k (k=ks*16+kh*8+j)
__global__ void k_split_B(const float* __restrict__ rain, _Float16* __restrict__ Bimg) {
    int id = blockIdx.x * 256 + threadIdx.x;
    if (id >= MM * 16) return;
    int cl = id & 31;
    int kp = (id >> 5) & 15;
    int tc = id >> 9;
    int row = tc * 32 + cl;
    const float4* src = (const float4*)(rain + (size_t)row * DD + kp * 8);
    float4 v0 = src[0], v1 = src[1];
    float x[8] = {v0.x, v0.y, v0.z, v0.w, v1.x, v1.y, v1.z, v1.w};
    _Float16 hi[8], lo[8];
    #pragma unroll
    for (int j = 0; j < 8; ++j) {
        _Float16 h = (_Float16)x[j];
        hi[j] = h;
        lo[j] = (_Float16)(x[j] - (float)h);
    }
    size_t base = (size_t)tc * 8192;
    int chunk = kp * 32 + cl;
    *(f16x8*)(Bimg + base + (size_t)chunk * 8) = *(f16x8*)hi;
    *(f16x8*)(Bimg + base + 4096 + (size_t)chunk * 8) = *(f16x8*)lo;
}

// MFMA distance GEMM + fused argmin.
// Triple-buffered B tiles, prefetch depth 2, raw s_barrier + manual vmcnt.
// 1-D grid b: split = b % 24 (== XCD-aligned), rb = b / 24.
__global__ __launch_bounds__(256, 2) void k_dist(
        const _Float16* __restrict__ Ahi, const _Float16* __restrict__ Alo,
        const _Float16* __restrict__ Bimg, const float* __restrict__ y2,
        u64* __restrict__ keys) {
    __shared__ _Float16 lds[3][8192];   // 3 x 16KB B-tile images
    __shared__ float y2s[672];          // this split's y2 values (<= 21 tiles * 32)

    const int tid = threadIdx.x;
    const int w = tid >> 6, lane = tid & 63;
    const int l5 = lane >> 5, l31 = lane & 31;
    const int b = blockIdx.x;
    const int split = b % SPLITS;
    const int n0 = (b / SPLITS) * 256;
    const int nt = (CT - split + SPLITS - 1) / SPLITS;   // 20 or 21

    // A fragments in registers, full K, 2 row-blocks per wave:
    // lane holds A[row = l31][k = ks*16 + l5*8 + j]
    f16x8 afh0[8], afl0[8], afh1[8], afl1[8];
    {
        int r0 = n0 + w * 64 + l31;       if (r0 >= NN) r0 = NN - 1;
        int r1 = n0 + w * 64 + 32 + l31;  if (r1 >= NN) r1 = NN - 1;
        const _Float16* h0 = Ahi + (size_t)r0 * DD + l5 * 8;
        const _Float16* o0 = Alo + (size_t)r0 * DD + l5 * 8;
        const _Float16* h1 = Ahi + (size_t)r1 * DD + l5 * 8;
        const _Float16* o1 = Alo + (size_t)r1 * DD + l5 * 8;
        #pragma unroll
        for (int ks = 0; ks < 8; ++ks) {
            afh0[ks] = *(const f16x8*)(h0 + ks * 16);
            afl0[ks] = *(const f16x8*)(o0 + ks * 16);
            afh1[ks] = *(const f16x8*)(h1 + ks * 16);
            afl1[ks] = *(const f16x8*)(o1 + ks * 16);
        }
    }

    // Stage this split's y2 into LDS (keeps the hot loop's y2 read off vmcnt)
    for (int j = tid; j < nt * 32; j += 256)
        y2s[j] = y2[(split + (j >> 5) * SPLITS) * 32 + (j & 31)];

    // Prologue: prefetch tiles 0,1 into bufs 0,1 (4 x 1KB segs per wave each)
    #pragma unroll
    for (int pi = 0; pi < 2; ++pi) {
        const _Float16* gsrc = Bimg + (size_t)(split + pi * SPLITS) * 8192;
        #pragma unroll
        for (int n = 0; n < 4; ++n) {
            int seg = w * 4 + n;
            __builtin_amdgcn_global_load_lds(
                (const __attribute__((address_space(1))) unsigned int*)
                    (gsrc + (size_t)seg * 512 + (size_t)lane * 8),
                (__attribute__((address_space(3))) unsigned int*)
                    (&lds[pi][0] + (size_t)seg * 512),
                16, 0, 0);
        }
    }
    __syncthreads();   // drains prologue prefetches + publishes y2s; vmcnt=0 here

    float bestd[32];
    int bestcol[32];
    #pragma unroll
    for (int s = 0; s < 32; ++s) { bestd[s] = 1e30f; bestcol[s] = 0; }

    int p = 0;   // current buffer = i % 3
    for (int i = 0; i < nt; ++i) {
        const int t = split + i * SPLITS;

        // Issue prefetch for tile i+2 into buf (p+2)%3 (freed at end of i-1)
        if (i + 2 < nt) {
            const _Float16* gsrc = Bimg + (size_t)(t + 2 * SPLITS) * 8192;
            _Float16* dst = &lds[(p + 2) % 3][0];
            #pragma unroll
            for (int n = 0; n < 4; ++n) {
                int seg = w * 4 + n;
                __builtin_amdgcn_global_load_lds(
                    (const __attribute__((address_space(1))) unsigned int*)
                        (gsrc + (size_t)seg * 512 + (size_t)lane * 8),
                    (__attribute__((address_space(3))) unsigned int*)
                        (dst + (size_t)seg * 512),
                    16, 0, 0);
            }
        }

        // Wait for this iteration's tile (i) without draining younger prefetches:
        // outstanding groups of 4: {pf(i),pf(i+1),pf(i+2)} minus already-drained.
        if (i + 2 < nt)      { __asm__ __volatile__("s_waitcnt vmcnt(8)" ::: "memory"); }
        else if (i + 1 < nt) { __asm__ __volatile__("s_waitcnt vmcnt(4)" ::: "memory"); }
        else                 { __asm__ __volatile__("s_waitcnt vmcnt(0)" ::: "memory"); }
        __builtin_amdgcn_s_barrier();
        __asm__ __volatile__("" ::: "memory");

        float y2v = y2s[i * 32 + l31];

        f32x16 acc0, acc1;
        #pragma unroll
        for (int e = 0; e < 16; ++e) { acc0[e] = y2v; acc1[e] = y2v; }

        const _Float16* lbuf = &lds[p][0];
        #pragma unroll
        for (int ks = 0; ks < 8; ++ks) {
            f16x8 bh = *(const f16x8*)(lbuf + (size_t)ks * 512 + (size_t)lane * 8);
            f16x8 bl = *(const f16x8*)(lbuf + 4096 + (size_t)ks * 512 + (size_t)lane * 8);
            acc0 = __builtin_amdgcn_mfma_f32_32x32x16_f16(afh0[ks], bh, acc0, 0, 0, 0);
            acc1 = __builtin_amdgcn_mfma_f32_32x32x16_f16(afh1[ks], bh, acc1, 0, 0, 0);
            acc0 = __builtin_amdgcn_mfma_f32_32x32x16_f16(afh0[ks], bl, acc0, 0, 0, 0);
            acc1 = __builtin_amdgcn_mfma_f32_32x32x16_f16(afh1[ks], bl, acc1, 0, 0, 0);
            acc0 = __builtin_amdgcn_mfma_f32_32x32x16_f16(afl0[ks], bh, acc0, 0, 0, 0);
            acc1 = __builtin_amdgcn_mfma_f32_32x32x16_f16(afl1[ks], bh, acc1, 0, 0, 0);
        }

        // Fold tile into running per-row argmin (col = t*32 + l31; y2 already in acc)
        int col = t * 32 + l31;
        #pragma unroll
        for (int e = 0; e < 16; ++e) {
            float d0 = acc0[e];
            bool u0 = d0 < bestd[e];
            bestd[e] = u0 ? d0 : bestd[e];
            bestcol[e] = u0 ? col : bestcol[e];
            float d1 = acc1[e];
            bool u1 = d1 < bestd[16 + e];
            bestd[16 + e] = u1 ? d1 : bestd[16 + e];
            bestcol[16 + e] = u1 ? col : bestcol[16 + e];
        }

        // All waves done reading buf p (ds_reads consumed by MFMAs above)
        __asm__ __volatile__("" ::: "memory");
        __builtin_amdgcn_s_barrier();
        __asm__ __volatile__("" ::: "memory");

        p = (p + 1) % 3;
    }

    // Cross-lane min over l31 group, then one atomicMin per row.
    // C/D layout: col=lane&31, row=(e&3)+8*(e>>2)+4*l5
    #pragma unroll
    for (int s = 0; s < 32; ++s) {
        unsigned u = __float_as_uint(bestd[s]);
        u = (u & 0x80000000u) ? ~u : (u | 0x80000000u);
        u64 key = ((u64)u << 32) | (unsigned)bestcol[s];
        #pragma unroll
        for (int off = 1; off < 32; off <<= 1) {
            u64 o = __shfl_xor(key, off);
            if (o < key) key = o;
        }
        if (l31 == 0) {
            int e = s & 15, rb2 = s >> 4;
            int grow = n0 + w * 64 + rb2 * 32 + (e & 3) + 8 * (e >> 2) + 4 * l5;
            if (grow < NN) atomicMin(&keys[grow], key);
        }
    }
}

// 16 rows per block: gather aligned, h=relu(comb@W1^T+b1), w=sigmoid(h@W2^T+b2),
// out = w*clear + (1-w)*aligned
__global__ __launch_bounds__(256) void k_mlp(const float* __restrict__ clear_f,
                                             const float* __restrict__ rain_f,
                                             const float* __restrict__ W1,
                                             const float* __restrict__ b1,
                                             const float* __restrict__ W2,
                                             const float* __restrict__ b2,
                                             const u64* __restrict__ keys,
                                             float* __restrict__ out) {
    __shared__ float comb_s[16][260];
    __shared__ float w1_s[64][133];
    __shared__ float red_s[16][17];
    __shared__ float w_s[16];

    const int tid = threadIdx.x;
    const int n0 = blockIdx.x * 16;

    {
        int r = tid >> 4;
        int t = tid & 15;
        int n = n0 + r;
        unsigned idx = (unsigned)(keys[n] & 0xffffffffu);
        const float4* cp = (const float4*)(clear_f + (size_t)n * DD);
        const float4* rp = (const float4*)(rain_f + (size_t)idx * DD);
        *(float4*)&comb_s[r][4 * t] = cp[t];
        *(float4*)&comb_s[r][4 * (t + 16)] = cp[t + 16];
        *(float4*)&comb_s[r][DD + 4 * t] = rp[t];
        *(float4*)&comb_s[r][DD + 4 * (t + 16)] = rp[t + 16];
    }

    const int r = tid & 15;
    const int g = tid >> 4;
    const int d8 = g * 8;
    float h[8] = {};
    for (int kt = 0; kt < 4; ++kt) {
        __syncthreads();
        #pragma unroll
        for (int i = 0; i < 32; ++i) {
            int lin = i * 256 + tid;
            int kk = lin & 63;
            int d = lin >> 6;
            w1_s[kk][d] = W1[(size_t)d * 256 + kt * 64 + kk];
        }
        __syncthreads();
        #pragma unroll
        for (int kk = 0; kk < 64; ++kk) {
            float c = comb_s[r][kt * 64 + kk];
            float4 wa = *(const float4*)&w1_s[kk][d8];
            float4 wb = *(const float4*)&w1_s[kk][d8 + 4];
            h[0] = fmaf(c, wa.x, h[0]);
            h[1] = fmaf(c, wa.y, h[1]);
            h[2] = fmaf(c, wa.z, h[2]);
            h[3] = fmaf(c, wa.w, h[3]);
            h[4] = fmaf(c, wb.x, h[4]);
            h[5] = fmaf(c, wb.y, h[5]);
            h[6] = fmaf(c, wb.z, h[6]);
            h[7] = fmaf(c, wb.w, h[7]);
        }
    }
    float part = 0.f;
    #pragma unroll
    for (int j = 0; j < 8; ++j) {
        float hv = h[j] + b1[d8 + j];
        hv = hv > 0.f ? hv : 0.f;
        part = fmaf(hv, W2[d8 + j], part);
    }
    red_s[r][g] = part;
    __syncthreads();
    if (tid < 16) {
        float s = 0.f;
        #pragma unroll
        for (int g2 = 0; g2 < 16; ++g2) s += red_s[tid][g2];
        s += b2[0];
        w_s[tid] = 1.f / (1.f + expf(-s));
    }
    __syncthreads();
    {
        int rw = tid >> 4;
        int c8 = (tid & 15) * 8;
        float wv = w_s[rw];
        float ov[8];
        #pragma unroll
        for (int j = 0; j < 8; ++j) {
            float cv = comb_s[rw][c8 + j];
            float av = comb_s[rw][DD + c8 + j];
            ov[j] = wv * cv + (1.f - wv) * av;
        }
        float4* o = (float4*)(out + (size_t)(n0 + rw) * DD + c8);
        o[0] = make_float4(ov[0], ov[1], ov[2], ov[3]);
        o[1] = make_float4(ov[4], ov[5], ov[6], ov[7]);
    }
}

extern "C" void kernel_launch(void* const* d_in, const int* in_sizes, int n_in,
                              void* d_out, int out_size, void* d_ws, size_t ws_size,
                              hipStream_t stream) {
    const float* clear_f = (const float*)d_in[0];
    const float* rain_f = (const float*)d_in[1];
    const float* W1 = (const float*)d_in[2];
    const float* b1 = (const float*)d_in[3];
    const float* W2 = (const float*)d_in[4];
    const float* b2 = (const float*)d_in[5];
    float* out = (float*)d_out;

    char* ws = (char*)d_ws;
    u64* keys = (u64*)ws;                                  // 160,000 B
    float* y2 = (float*)(ws + 160000);                     // 64,000 B
    _Float16* Ahi = (_Float16*)(ws + 224000);              // 5,120,000 B
    _Float16* Alo = (_Float16*)(ws + 5344000);             // 5,120,000 B
    _Float16* Bimg = (_Float16*)(ws + 10464000);           // 8,192,000 B

    k_init_keys<<<(NN + 255) / 256, 256, 0, stream>>>(keys);
    k_y2<<<MM / 4, 256, 0, stream>>>(rain_f, y2);
    k_split_A<<<(NN * 16 + 255) / 256, 256, 0, stream>>>(clear_f, Ahi, Alo);
    k_split_B<<<(MM * 16 + 255) / 256, 256, 0, stream>>>(rain_f, Bimg);
    k_dist<<<RB * SPLITS, 256, 0, stream>>>(Ahi, Alo, Bimg, y2, keys);
    k_mlp<<<NN / 16, 256, 0, stream>>>(clear_f, rain_f, W1, b1, W2, b2, keys, out);
}

// Round 7
// 356.396 us; speedup vs baseline: 10.1510x; 1.0690x over previous
//
#include <hip/hip_runtime.h>
#include <stdint.h>

#define NN 20000
#define MM 16000
#define DD 128
#define CT2 250       // 16000 / 64 col-tiles
#define SPLITS 32     // multiple of 8 -> split % 8 == XCD id (L2 locality)
#define RB 79         // ceil(20000/256) row blocks

typedef unsigned long long u64;
typedef _Float16 f16x8 __attribute__((ext_vector_type(8)));
typedef float f32x16 __attribute__((ext_vector_type(16)));

// One wave per rain row: y2[m] = ||rain[m]||^2 (fp32, NO bias — r5/r6's +512
// bias coarsened accumulator ulp 8x and flipped near-tie argmins)
__global__ void k_y2(const float* __restrict__ rain, float* __restrict__ y2) {
    int row = blockIdx.x * 4 + (threadIdx.x >> 6);
    int lane = threadIdx.x & 63;
    if (row >= MM) return;
    float2 v = ((const float2*)(rain + (size_t)row * DD))[lane];
    float s = v.x * v.x + v.y * v.y;
    #pragma unroll
    for (int off = 32; off > 0; off >>= 1) s += __shfl_down(s, off);
    if (lane == 0) y2[row] = s;
}

// Split rain into fp16 hi/lo 64-col tile images (32KB per tile):
// tile tc: hi f16[0:8192], lo f16[8192:16384]
// chunk(ks,cg,kh,cl) = ((ks*2+cg)*2+kh)*32+cl; payload = 8 consecutive k,
// k = ks*16+kh*8+j, col = cg*32+cl.
__global__ void k_split_B(const float* __restrict__ rain, _Float16* __restrict__ Bimg) {
    int id = blockIdx.x * 256 + threadIdx.x;
    if (id >= CT2 * 1024) return;
    int cl = id & 31;
    int cg = (id >> 5) & 1;
    int kp = (id >> 6) & 15;           // ks = kp>>1, kh = kp&1
    int tc = id >> 10;
    int row = tc * 64 + cg * 32 + cl;
    const float4* src = (const float4*)(rain + (size_t)row * DD + kp * 8);
    float4 v0 = src[0], v1 = src[1];
    float x[8] = {v0.x, v0.y, v0.z, v0.w, v1.x, v1.y, v1.z, v1.w};
    _Float16 hi[8], lo[8];
    #pragma unroll
    for (int j = 0; j < 8; ++j) {
        _Float16 h = (_Float16)x[j];
        hi[j] = h;
        lo[j] = (_Float16)(x[j] - (float)h);
    }
    int ks = kp >> 1, kh = kp & 1;
    int chunk = ((ks * 2 + cg) * 2 + kh) * 32 + cl;
    size_t base = (size_t)tc * 16384;
    *(f16x8*)(Bimg + base + (size_t)chunk * 8) = *(f16x8*)hi;
    *(f16x8*)(Bimg + base + 8192 + (size_t)chunk * 8) = *(f16x8*)lo;
}

// W1 -> fp16 B-image for the MLP GEMM: chunk c = ((ks*4+cg)*2+kh)*32+cl;
// B[k][d] = W1[d][k], k = ks*16+kh*8+j, d = cg*32+cl. 4096 chunks = 64KB.
__global__ void k_w1img(const float* __restrict__ W1, _Float16* __restrict__ W1img) {
    int id = blockIdx.x * 256 + threadIdx.x;
    if (id >= 4096) return;
    int cl = id & 31;
    int kh = (id >> 5) & 1;
    int cg = (id >> 6) & 3;
    int ks = id >> 8;
    int d = cg * 32 + cl;
    int k = ks * 16 + kh * 8;
    const float4* src = (const float4*)(W1 + (size_t)d * 256 + k);
    float4 v0 = src[0], v1 = src[1];
    float x[8] = {v0.x, v0.y, v0.z, v0.w, v1.x, v1.y, v1.z, v1.w};
    _Float16 h[8];
    #pragma unroll
    for (int j = 0; j < 8; ++j) h[j] = (_Float16)x[j];
    *(f16x8*)(W1img + (size_t)id * 8) = *(f16x8*)h;
}

// MFMA distance GEMM + fused argmin. Block = 256 rows x 64-col tiles.
// Wave w: rows w*64..w*64+63 (2 row-blocks), both col-groups.
// Double-buffered 32KB tiles, ONE __syncthreads per iter. A split in-kernel.
// Numerics = r4-proven: acc init = y2 (unbiased), hh/hl/lh per ks.
__global__ __launch_bounds__(256, 2) void k_dist(
        const float* __restrict__ clear_f,
        const _Float16* __restrict__ Bimg, const float* __restrict__ y2,
        u64* __restrict__ keys2) {
    __shared__ _Float16 lds[2][16384];   // 2 x 32KB B-tile images

    const int tid = threadIdx.x;
    const int w = tid >> 6, lane = tid & 63;
    const int l5 = lane >> 5, l31 = lane & 31;
    const int b = blockIdx.x;
    const int split = b & 31;
    const int n0 = (b >> 5) * 256;
    const int nt = (CT2 - split + SPLITS - 1) / SPLITS;   // 7 or 8

    // Prologue prefetch: tile 0 -> buf 0 (32 segs of 1KB; 8 per wave)
    {
        const _Float16* gsrc = Bimg + (size_t)split * 16384;
        #pragma unroll
        for (int n = 0; n < 8; ++n) {
            int seg = w * 8 + n;
            __builtin_amdgcn_global_load_lds(
                (const __attribute__((address_space(1))) unsigned int*)
                    (gsrc + (size_t)seg * 512 + (size_t)lane * 8),
                (__attribute__((address_space(3))) unsigned int*)
                    (&lds[0][0] + (size_t)seg * 512),
                16, 0, 0);
        }
    }

    // A fragments: lane holds A[row=l31 of rb][k=ks*16+l5*8+j], split in-kernel
    f16x8 afh[2][8], afl[2][8];
    #pragma unroll
    for (int rb = 0; rb < 2; ++rb) {
        int r = n0 + w * 64 + rb * 32 + l31;
        if (r >= NN) r = NN - 1;
        const float* ap = clear_f + (size_t)r * DD + l5 * 8;
        #pragma unroll
        for (int ks = 0; ks < 8; ++ks) {
            float4 v0 = *(const float4*)(ap + ks * 16);
            float4 v1 = *(const float4*)(ap + ks * 16 + 4);
            float x[8] = {v0.x, v0.y, v0.z, v0.w, v1.x, v1.y, v1.z, v1.w};
            _Float16 hi[8], lo[8];
            #pragma unroll
            for (int j = 0; j < 8; ++j) {
                float s = -2.f * x[j];
                _Float16 h = (_Float16)s;
                hi[j] = h;
                lo[j] = (_Float16)(s - (float)h);
            }
            afh[rb][ks] = *(f16x8*)hi;
            afl[rb][ks] = *(f16x8*)lo;
        }
    }
    __syncthreads();   // buf 0 ready

    float bestd[32];
    unsigned bits[4] = {0u, 0u, 0u, 0u};   // nibble/slot: (tile_idx<<1)|cg
    #pragma unroll
    for (int s = 0; s < 32; ++s) bestd[s] = 1e30f;

    int p = 0;
    for (int i = 0; i < nt; ++i) {
        const int t = split + i * SPLITS;

        // Prefetch next tile into the other buffer (overlaps compute on buf p)
        if (i + 1 < nt) {
            const _Float16* gsrc = Bimg + (size_t)(t + SPLITS) * 16384;
            _Float16* dst = &lds[1 - p][0];
            #pragma unroll
            for (int n = 0; n < 8; ++n) {
                int seg = w * 8 + n;
                __builtin_amdgcn_global_load_lds(
                    (const __attribute__((address_space(1))) unsigned int*)
                        (gsrc + (size_t)seg * 512 + (size_t)lane * 8),
                    (__attribute__((address_space(3))) unsigned int*)
                        (dst + (size_t)seg * 512),
                    16, 0, 0);
            }
        }

        float y2v0 = y2[t * 64 + l31];
        float y2v1 = y2[t * 64 + 32 + l31];

        // 4 independent accumulator chains (rb x cg); C-init carries y2
        f32x16 acc00, acc01, acc10, acc11;
        #pragma unroll
        for (int e = 0; e < 16; ++e) {
            acc00[e] = y2v0; acc10[e] = y2v0;
            acc01[e] = y2v1; acc11[e] = y2v1;
        }

        const _Float16* lbuf = &lds[p][0];
        #pragma unroll
        for (int ks = 0; ks < 8; ++ks) {
            f16x8 bh0 = *(const f16x8*)(lbuf + (size_t)(ks * 2 + 0) * 512 + (size_t)lane * 8);
            f16x8 bh1 = *(const f16x8*)(lbuf + (size_t)(ks * 2 + 1) * 512 + (size_t)lane * 8);
            f16x8 bl0 = *(const f16x8*)(lbuf + 8192 + (size_t)(ks * 2 + 0) * 512 + (size_t)lane * 8);
            f16x8 bl1 = *(const f16x8*)(lbuf + 8192 + (size_t)(ks * 2 + 1) * 512 + (size_t)lane * 8);
            // round-robin the 4 chains: waves of 4 independent MFMAs
            acc00 = __builtin_amdgcn_mfma_f32_32x32x16_f16(afh[0][ks], bh0, acc00, 0, 0, 0);
            acc10 = __builtin_amdgcn_mfma_f32_32x32x16_f16(afh[1][ks], bh0, acc10, 0, 0, 0);
            acc01 = __builtin_amdgcn_mfma_f32_32x32x16_f16(afh[0][ks], bh1, acc01, 0, 0, 0);
            acc11 = __builtin_amdgcn_mfma_f32_32x32x16_f16(afh[1][ks], bh1, acc11, 0, 0, 0);
            acc00 = __builtin_amdgcn_mfma_f32_32x32x16_f16(afh[0][ks], bl0, acc00, 0, 0, 0);
            acc10 = __builtin_amdgcn_mfma_f32_32x32x16_f16(afh[1][ks], bl0, acc10, 0, 0, 0);
            acc01 = __builtin_amdgcn_mfma_f32_32x32x16_f16(afh[0][ks], bl1, acc01, 0, 0, 0);
            acc11 = __builtin_amdgcn_mfma_f32_32x32x16_f16(afh[1][ks], bl1, acc11, 0, 0, 0);
            acc00 = __builtin_amdgcn_mfma_f32_32x32x16_f16(afl[0][ks], bh0, acc00, 0, 0, 0);
            acc10 = __builtin_amdgcn_mfma_f32_32x32x16_f16(afl[1][ks], bh0, acc10, 0, 0, 0);
            acc01 = __builtin_amdgcn_mfma_f32_32x32x16_f16(afl[0][ks], bh1, acc01, 0, 0, 0);
            acc11 = __builtin_amdgcn_mfma_f32_32x32x16_f16(afl[1][ks], bh1, acc11, 0, 0, 0);
        }

        // Fold: cg-pair min first (strict < prefers cg0 = lower col on tie),
        // then strict < vs running best (prefers earlier tile = lower col)
        const unsigned ibase = (unsigned)i << 1;
        #pragma unroll
        for (int e = 0; e < 16; ++e) {
            {
                float d0 = acc00[e], d1 = acc01[e];
                bool tk = d1 < d0;
                float dm = tk ? d1 : d0;
                int s = e, sh = 4 * (e & 7);
                bool up = dm < bestd[s];
                bestd[s] = up ? dm : bestd[s];
                unsigned nib = ibase | (unsigned)tk;
                bits[s >> 3] = up ? ((bits[s >> 3] & ~(15u << sh)) | (nib << sh))
                                  : bits[s >> 3];
            }
            {
                float d0 = acc10[e], d1 = acc11[e];
                bool tk = d1 < d0;
                float dm = tk ? d1 : d0;
                int s = 16 + e, sh = 4 * (s & 7);
                bool up = dm < bestd[s];
                bestd[s] = up ? dm : bestd[s];
                unsigned nib = ibase | (unsigned)tk;
                bits[s >> 3] = up ? ((bits[s >> 3] & ~(15u << sh)) | (nib << sh))
                                  : bits[s >> 3];
            }
        }

        __syncthreads();   // publishes prefetch (buf 1-p), frees buf p
        p ^= 1;
    }

    // Cross-lane min over the 32 l31 lanes, then one plain store per row.
    // Monotone sign-flip map (distances can be negative near the min!).
    // C/D layout: col=lane&31, row=(e&3)+8*(e>>2)+4*l5
    #pragma unroll
    for (int s = 0; s < 32; ++s) {
        unsigned nib = (bits[s >> 3] >> (4 * (s & 7))) & 15u;
        int i4 = (int)(nib >> 1), cg = (int)(nib & 1);
        int col = (split + i4 * SPLITS) * 64 + cg * 32 + l31;
        unsigned u = __float_as_uint(bestd[s]);
        u = (u & 0x80000000u) ? ~u : (u | 0x80000000u);
        u64 key = ((u64)u << 32) | (unsigned)col;
        #pragma unroll
        for (int off = 1; off < 32; off <<= 1) {
            u64 o = __shfl_xor(key, off);
            if (o < key) key = o;
        }
        if (l31 == 0) {
            int e = s & 15, rb = s >> 4;
            int grow = n0 + w * 64 + rb * 32 + (e & 3) + 8 * (e >> 2) + 4 * l5;
            if (grow < NN) keys2[(size_t)grow * SPLITS + split] = key;
        }
    }
}

// Final argmin over the 32 split winners per row -> int index
__global__ void k_reduce(const u64* __restrict__ keys2, int* __restrict__ idx) {
    int n = blockIdx.x * 256 + threadIdx.x;
    if (n >= NN) return;
    const u64* p = keys2 + (size_t)n * SPLITS;
    u64 best = ~0ull;
    #pragma unroll
    for (int j = 0; j < SPLITS; ++j) {
        u64 k = p[j];
        if (k < best) best = k;
    }
    idx[n] = (int)(best & 0xffffffffu);
}

// MLP via fp16 MFMA: block = 128 rows (wave w: rows n0+w*32..+31).
// A-frag = comb row (clear|aligned) gathered+cvt straight into registers;
// B = W1 image staged once per block in LDS (64KB).
__global__ __launch_bounds__(256, 2) void k_mlp(
        const float* __restrict__ clear_f, const float* __restrict__ rain_f,
        const _Float16* __restrict__ W1img, const float* __restrict__ b1,
        const float* __restrict__ W2, const float* __restrict__ b2,
        const int* __restrict__ idx, float* __restrict__ out) {
    __shared__ _Float16 w1s[32768];   // 64KB

    const int tid = threadIdx.x;
    const int w = tid >> 6, lane = tid & 63;
    const int l5 = lane >> 5, l31 = lane & 31;
    const int n0 = blockIdx.x * 128;

    // Stage W1 image: 64 segs of 1KB
    #pragma unroll
    for (int n = 0; n < 16; ++n) {
        int seg = w * 16 + n;
        __builtin_amdgcn_global_load_lds(
            (const __attribute__((address_space(1))) unsigned int*)
                (W1img + (size_t)seg * 512 + (size_t)lane * 8),
            (__attribute__((address_space(3))) unsigned int*)
                (&w1s[0] + (size_t)seg * 512),
            16, 0, 0);
    }

    // Gather A-fragments: row = l31's comb row; k<128 clear, k>=128 aligned
    int n = n0 + w * 32 + l31;
    int nc = n < NN ? n : NN - 1;
    int rid = idx[nc];
    f16x8 af[16];
    #pragma unroll
    for (int ks = 0; ks < 16; ++ks) {
        int k0 = ks * 16 + l5 * 8;
        const float4* src = (k0 < 128)
            ? (const float4*)(clear_f + (size_t)nc * DD + k0)
            : (const float4*)(rain_f + (size_t)rid * DD + (k0 - 128));
        float4 v0 = src[0], v1 = src[1];
        float x[8] = {v0.x, v0.y, v0.z, v0.w, v1.x, v1.y, v1.z, v1.w};
        _Float16 h[8];
        #pragma unroll
        for (int j = 0; j < 8; ++j) h[j] = (_Float16)x[j];
        af[ks] = *(f16x8*)h;
    }

    __syncthreads();   // w1s ready

    f32x16 acc[4];
    #pragma unroll
    for (int cg = 0; cg < 4; ++cg)
        #pragma unroll
        for (int e = 0; e < 16; ++e) acc[cg][e] = 0.f;

    #pragma unroll
    for (int ks = 0; ks < 16; ++ks) {
        #pragma unroll
        for (int cg = 0; cg < 4; ++cg) {
            f16x8 bh = *(const f16x8*)(&w1s[0] +
                ((size_t)((ks * 4 + cg) * 2 + l5)) * 256 + (size_t)l31 * 8);
            acc[cg] = __builtin_amdgcn_mfma_f32_32x32x16_f16(af[ks], bh, acc[cg], 0, 0, 0);
        }
    }

    // Epilogue: lane holds h[row(e,l5)][d = cg*32 + l31]
    float b1v[4], w2v[4];
    #pragma unroll
    for (int cg = 0; cg < 4; ++cg) {
        b1v[cg] = b1[cg * 32 + l31];
        w2v[cg] = W2[cg * 32 + l31];
    }
    float b2v = b2[0];

    #pragma unroll
    for (int e = 0; e < 16; ++e) {
        float part = 0.f;
        #pragma unroll
        for (int cg = 0; cg < 4; ++cg) {
            float hv = acc[cg][e] + b1v[cg];
            hv = hv > 0.f ? hv : 0.f;
            part = fmaf(hv, w2v[cg], part);
        }
        #pragma unroll
        for (int off = 1; off < 32; off <<= 1) part += __shfl_xor(part, off);
        float s = part + b2v;
        float wv = 1.f / (1.f + expf(-s));
        int row = n0 + w * 32 + (e & 3) + 8 * (e >> 2) + 4 * l5;
        if (row < NN) {
            int rid2 = idx[row];
            float4 cv = *(const float4*)(clear_f + (size_t)row * DD + l31 * 4);
            float4 av = *(const float4*)(rain_f + (size_t)rid2 * DD + l31 * 4);
            float4 ov;
            ov.x = wv * cv.x + (1.f - wv) * av.x;
            ov.y = wv * cv.y + (1.f - wv) * av.y;
            ov.z = wv * cv.z + (1.f - wv) * av.z;
            ov.w = wv * cv.w + (1.f - wv) * av.w;
            *(float4*)(out + (size_t)row * DD + l31 * 4) = ov;
        }
    }
}

extern "C" void kernel_launch(void* const* d_in, const int* in_sizes, int n_in,
                              void* d_out, int out_size, void* d_ws, size_t ws_size,
                              hipStream_t stream) {
    const float* clear_f = (const float*)d_in[0];
    const float* rain_f = (const float*)d_in[1];
    const float* W1 = (const float*)d_in[2];
    const float* b1 = (const float*)d_in[3];
    const float* W2 = (const float*)d_in[4];
    const float* b2 = (const float*)d_in[5];
    float* out = (float*)d_out;

    char* ws = (char*)d_ws;
    u64* keys2 = (u64*)ws;                                 // 5,120,000 B
    int* idx = (int*)(ws + 5120000);                       // 80,000 B
    float* y2 = (float*)(ws + 5200000);                    // 64,000 B
    _Float16* Bimg = (_Float16*)(ws + 5264000);            // 8,192,000 B
    _Float16* W1img = (_Float16*)(ws + 13456000);          // 65,536 B  (end 13.52MB)

    k_y2<<<MM / 4, 256, 0, stream>>>(rain_f, y2);
    k_split_B<<<(CT2 * 1024 + 255) / 256, 256, 0, stream>>>(rain_f, Bimg);
    k_w1img<<<16, 256, 0, stream>>>(W1, W1img);
    k_dist<<<RB * SPLITS, 256, 0, stream>>>(clear_f, Bimg, y2, keys2);
    k_reduce<<<(NN + 255) / 256, 256, 0, stream>>>(keys2, idx);
    k_mlp<<<(NN + 127) / 128, 256, 0, stream>>>(clear_f, rain_f, W1img, b1, W2, b2, idx, out);
}